// Round 1
// 926.762 us; speedup vs baseline: 1.0097x; 1.0097x over previous
//
#include <hip/hip_runtime.h>
#include <hip/hip_bf16.h>
#include <stdint.h>

// Problem constants
#define G 32
#define NN 1024
#define EE 16384
#define FIN 128
#define HID 1024
#define OUT 4096
#define BB 32
#define SS 256

typedef __bf16 bf16_t;
typedef __attribute__((ext_vector_type(2))) __bf16 bf16x2;
typedef __attribute__((ext_vector_type(8))) __bf16 bf16x8;
typedef __attribute__((ext_vector_type(4))) float f32x4;

// ---------------- workspace layout (bytes) ----------------
// zeroed block (one memset of WS_ZERO_BYTES at WS_CNT):
#define WS_CNT      4096         // G*NN*4      = 131072
#define WS_WNODE    135168       // G*NN*4
#define WS_HSUM     266240       // G*NN*4
#define WS_WSUM     397312       // G*NN*4
#define WS_EMB      528384       // G*OUT*4     = 524288
#define WS_ZERO_BYTES 1048576    // covers cnt..emb exactly
#define WS_ROWPTR   1052672      // G*NN*4
#define WS_CURSOR   1183744      // G*NN*4
#define WS_POS2G    1314816      // BB*SS*4     = 32768
#define WS_B1F      1347584      // HID*4       = 4096
#define WS_B2F      1351680      // OUT*4       = 16384
#define WS_ESRC     1368064      // G*EE*4      = 2097152
#define WS_XBF      3465216      // G*NN*FIN*2  = 8388608
#define WS_AGG      11853824     // G*NN*FIN*2  = 8388608
#define WS_WCATT    20242432     // HID*256*2   = 524288

__device__ inline float ldf(const void* p, size_t i, int f32) {
    return f32 ? ((const float*)p)[i] : (float)((const bf16_t*)p)[i];
}

// ---------------- inline dtype probe ----------------
// Deterministic: every caller reads the SAME 1 KB window of node_features
// (L1/L2-hot), so all blocks reach the same verdict with no flag round-trip.
// fp32 data: even bf16 slots are low-mantissa bits -> bits 13&14 both set
// w.p. 0.25/sample; 256 samples -> miss prob 0.75^256 ~ 2e-32.
// Genuine bf16 normals (|x| < 2^65) never have exp bits 7&6 both set.
__device__ inline int probe_f32(const void* xp) {
    const uint4* u = (const uint4*)xp;
    unsigned accm = 0;
    #pragma unroll 4
    for (int i = 0; i < 64; ++i) {
        uint4 v = u[i];
        accm |= (v.x & (v.x << 1));
        accm |= (v.y & (v.y << 1));
        accm |= (v.z & (v.z << 1));
        accm |= (v.w & (v.w << 1));
    }
    return (accm >> 14) & 1;  // bit14 = (low-short bit14 & bit13)
}

// async global->LDS, 16 B per lane (dest = wave-uniform base + lane*16;
// per-lane pointer computed in lane order is equivalent and safe)
__device__ inline void gl_lds16(const bf16_t* g, bf16_t* l) {
    __builtin_amdgcn_global_load_lds(
        (const __attribute__((address_space(1))) void*)g,
        (__attribute__((address_space(3))) void*)l, 16, 0, 0);
}

// canonicalize x -> bf16 xbf; tail blocks canonicalize b1,b2 -> fp32
__global__ __launch_bounds__(256) void conv_x_k(const void* x, const void* b1,
                                                const void* b2,
                                                bf16_t* __restrict__ xbf,
                                                float* __restrict__ b1f,
                                                float* __restrict__ b2f) {
    int f32 = probe_f32(x);
    int bx = blockIdx.x;
    if (bx < 4096) {
        size_t i = ((size_t)bx * 256 + threadIdx.x) * 4;
        if (f32) {
            const float* xf = (const float*)x;
            bf16_t o0 = (bf16_t)xf[i], o1 = (bf16_t)xf[i + 1],
                   o2 = (bf16_t)xf[i + 2], o3 = (bf16_t)xf[i + 3];
            unsigned short p[4] = {*(unsigned short*)&o0, *(unsigned short*)&o1,
                                   *(unsigned short*)&o2, *(unsigned short*)&o3};
            *(uint2*)(xbf + i) = *(uint2*)p;
        } else {
            *(uint2*)(xbf + i) = *(const uint2*)((const bf16_t*)x + i);
        }
    } else {
        int t = (bx - 4096) * 256 + threadIdx.x;
        if (t < HID) b1f[t] = ldf(b1, t, f32);
        else if (t < HID + OUT) b2f[t - HID] = ldf(b2, t - HID, f32);
    }
}

// ---------------- CSR build ----------------
__global__ __launch_bounds__(256) void count_edges_k(const int* __restrict__ ei,
                                                     int* __restrict__ cnt) {
    int idx = blockIdx.x * 256 + threadIdx.x;
    int g = idx >> 14, e = idx & (EE - 1);
    int dst = ei[(g * 2 + 1) * EE + e];
    atomicAdd(&cnt[g * NN + dst], 1);
}

__global__ __launch_bounds__(256) void scan_rowptr_k(const int* __restrict__ cnt,
                                                     int* __restrict__ rowptr,
                                                     int* __restrict__ cursor) {
    int g = blockIdx.x;
    const int* c = cnt + g * NN;
    __shared__ int part[256];
    int t = threadIdx.x;
    int c0 = c[t * 4], c1 = c[t * 4 + 1], c2 = c[t * 4 + 2], c3 = c[t * 4 + 3];
    int s = c0 + c1 + c2 + c3;
    part[t] = s;
    __syncthreads();
    for (int off = 1; off < 256; off <<= 1) {
        int v = (t >= off) ? part[t - off] : 0;
        __syncthreads();
        part[t] += v;
        __syncthreads();
    }
    int base = part[t] - s;
    int gi = g * NN + t * 4;
    int o0 = base, o1 = o0 + c0, o2 = o1 + c1, o3 = o2 + c2;
    rowptr[gi] = o0; rowptr[gi + 1] = o1; rowptr[gi + 2] = o2; rowptr[gi + 3] = o3;
    cursor[gi] = o0; cursor[gi + 1] = o1; cursor[gi + 2] = o2; cursor[gi + 3] = o3;
}

// fused: scatter edges into CSR + accumulate wnode[src] += 1/deg[dst]
__global__ __launch_bounds__(256) void scatter_edges_k(const int* __restrict__ ei,
                                                       const int* __restrict__ cnt,
                                                       int* __restrict__ cursor,
                                                       int* __restrict__ esrc,
                                                       float* __restrict__ wnode) {
    int idx = blockIdx.x * 256 + threadIdx.x;
    int g = idx >> 14, e = idx & (EE - 1);
    int src = ei[g * 2 * EE + e];
    int dst = ei[(g * 2 + 1) * EE + e];
    int c = cnt[g * NN + dst];
    atomicAdd(&wnode[g * NN + src], 1.0f / (float)(c > 1 ? c : 1));
    int p = atomicAdd(&cursor[g * NN + dst], 1);
    esrc[g * EE + p] = src;
}

// mean-aggregate xbf over incoming edges -> agg (bf16). One wave per node,
// ushort2 per lane; start/deg forced wave-uniform -> scalar esrc walk.
__global__ __launch_bounds__(256) void aggregate_k(const bf16_t* __restrict__ x,
                                                   const int* __restrict__ rowptr,
                                                   const int* __restrict__ cnt,
                                                   const int* __restrict__ esrc,
                                                   bf16_t* __restrict__ agg) {
    int g = blockIdx.x >> 8;
    int nb = blockIdx.x & 255;
    int wave = threadIdx.x >> 6;
    int lane = threadIdx.x & 63;
    int n = nb * 4 + wave;
    int start = __builtin_amdgcn_readfirstlane(rowptr[g * NN + n]);
    int deg   = __builtin_amdgcn_readfirstlane(cnt[g * NN + n]);
    const bf16_t* xg = x + (size_t)g * NN * FIN;
    const int* es = esrc + g * EE;
    int f = lane * 2;
    float s0 = 0.f, s1 = 0.f;
    for (int i = 0; i < deg; ++i) {
        int s = es[start + i];
        bf16x2 v = *(const bf16x2*)(xg + s * FIN + f);
        s0 += (float)v[0];
        s1 += (float)v[1];
    }
    float inv = 1.0f / (float)(deg > 1 ? deg : 1);
    bf16x2 o;
    o[0] = (bf16_t)(s0 * inv);
    o[1] = (bf16_t)(s1 * inv);
    *(bf16x2*)(agg + ((size_t)g * NN + n) * FIN + f) = o;
}

// WcatT[n][k]: k<128 -> Wl1[k][n], else Wr1[k-128][n]   ([HID][256] bf16)
__global__ __launch_bounds__(256) void build_wcatT_k(const void* Wl1, const void* Wr1,
                                                     const void* x,
                                                     bf16_t* __restrict__ wcatT) {
    int f32 = probe_f32(x);
    int n = blockIdx.x;
    int k = threadIdx.x;
    float v = (k < 128) ? ldf(Wl1, (size_t)k * HID + n, f32)
                        : ldf(Wr1, (size_t)(k - 128) * HID + n, f32);
    wcatT[n * 256 + k] = (bf16_t)v;
}

// Layer-1 GEMM: relu([agg|x] @ [Wl1;Wr1] + b1) with fused plain/weighted
// row-sums. m97 structure: global_load_lds(16B) staging, linear [128][32] LDS
// (T2 swizzle is measured-null at 128-tile/2-phase), 2 barriers per K-step.
__global__ __launch_bounds__(256) void l1_gemm_k(const bf16_t* __restrict__ agg,
                                                 const bf16_t* __restrict__ x,
                                                 const bf16_t* __restrict__ wcatT,
                                                 const float* __restrict__ b1f,
                                                 const float* __restrict__ wnode,
                                                 float* __restrict__ hsum,
                                                 float* __restrict__ wsum) {
    int nt = blockIdx.x, mt = blockIdx.y, g = blockIdx.z;
    __shared__ bf16_t As[128 * 32];
    __shared__ bf16_t Bs[128 * 32];
    int tid = threadIdx.x;
    int lane = tid & 63, wave = tid >> 6;
    int quad = lane >> 4, l16 = lane & 15;
    int m0 = (wave >> 1) * 64, n0 = (wave & 1) * 64;

    f32x4 acc[4][4] = {};
    const size_t arow = ((size_t)g * NN + (size_t)mt * 128) * FIN;
    const bf16_t* bslab = wcatT + (size_t)(nt * 128) * 256;

    // staging geometry: linear 16B chunk j -> row = j>>2, col = (j&3)*8
    int j0 = tid,        row0 = j0 >> 2, sl0 = (j0 & 3) * 8;
    int j1 = 256 + tid,  row1 = j1 >> 2, sl1 = (j1 & 3) * 8;

    for (int kc = 0; kc < 8; ++kc) {
        int k0 = kc * 32;
        const bf16_t* asrc = (k0 < 128) ? (agg + arow + k0) : (x + arow + (k0 - 128));
        const bf16_t* bsrc = bslab + k0;
        gl_lds16(asrc + (size_t)row0 * FIN + sl0, &As[j0 * 8]);
        gl_lds16(asrc + (size_t)row1 * FIN + sl1, &As[j1 * 8]);
        gl_lds16(bsrc + (size_t)row0 * 256 + sl0, &Bs[j0 * 8]);
        gl_lds16(bsrc + (size_t)row1 * 256 + sl1, &Bs[j1 * 8]);
        __syncthreads();  // drains vmcnt -> LDS tiles complete
        bf16x8 a[4], b[4];
        int kl = quad * 8;
        #pragma unroll
        for (int t4 = 0; t4 < 4; ++t4) {
            a[t4] = *(const bf16x8*)(&As[(m0 + t4 * 16 + l16) * 32 + kl]);
            b[t4] = *(const bf16x8*)(&Bs[(n0 + t4 * 16 + l16) * 32 + kl]);
        }
        #pragma unroll
        for (int ti = 0; ti < 4; ++ti)
            #pragma unroll
            for (int tj = 0; tj < 4; ++tj)
                acc[ti][tj] = __builtin_amdgcn_mfma_f32_16x16x32_bf16(a[ti], b[tj], acc[ti][tj], 0, 0, 0);
        __syncthreads();
    }

    const float* wn = wnode + (size_t)g * NN + mt * 128;
    #pragma unroll
    for (int tj = 0; tj < 4; ++tj) {
        int ng = nt * 128 + n0 + tj * 16 + l16;
        float bias = b1f[ng];
        float hs = 0.f, wsv = 0.f;
        #pragma unroll
        for (int ti = 0; ti < 4; ++ti) {
            int mb = m0 + ti * 16 + quad * 4;
            #pragma unroll
            for (int r = 0; r < 4; ++r) {
                float h = acc[ti][tj][r] + bias;
                h = h > 0.f ? h : 0.f;
                hs += h;
                wsv += wn[mb + r] * h;
            }
        }
        hs += __shfl_xor(hs, 16);  hs += __shfl_xor(hs, 32);
        wsv += __shfl_xor(wsv, 16); wsv += __shfl_xor(wsv, 32);
        if (quad == 0) {
            atomicAdd(&hsum[(size_t)g * HID + ng], hs);
            atomicAdd(&wsum[(size_t)g * HID + ng], wsv);
        }
    }
}

// Layer-2 collapsed GEMV (dtype-dual weight reads)
__global__ __launch_bounds__(256) void l2_gemv_k(const float* __restrict__ wsum,
                                                 const float* __restrict__ hsum,
                                                 const void* Wl2v, const void* Wr2v,
                                                 const void* x,
                                                 float* __restrict__ emb_acc) {
    int f32 = probe_f32(x);
    int jc = blockIdx.x;   // 16
    int kc = blockIdx.y;   // 8
    int t = threadIdx.x;
    int j = jc * 256 + t;
    __shared__ float u1[G][128];
    __shared__ float u2[G][128];
    for (int i = 0; i < 16; ++i) {
        int idx = t + i * 256;
        int g = idx >> 7, kk = idx & 127;
        u1[g][kk] = wsum[g * HID + kc * 128 + kk] * (1.0f / 1024.0f);
        u2[g][kk] = hsum[g * HID + kc * 128 + kk] * (1.0f / 1024.0f);
    }
    __syncthreads();
    float acc[G] = {};
    if (f32) {
        const float* L = (const float*)Wl2v;
        const float* R = (const float*)Wr2v;
        for (int kk = 0; kk < 128; ++kk) {
            size_t krow = (size_t)(kc * 128 + kk);
            float wl = L[krow * OUT + j];
            float wr = R[krow * OUT + j];
            #pragma unroll
            for (int g = 0; g < G; ++g)
                acc[g] = fmaf(u1[g][kk], wl, fmaf(u2[g][kk], wr, acc[g]));
        }
    } else {
        const bf16_t* L = (const bf16_t*)Wl2v;
        const bf16_t* R = (const bf16_t*)Wr2v;
        for (int kk = 0; kk < 128; ++kk) {
            size_t krow = (size_t)(kc * 128 + kk);
            float wl = (float)L[krow * OUT + j];
            float wr = (float)R[krow * OUT + j];
            #pragma unroll
            for (int g = 0; g < G; ++g)
                acc[g] = fmaf(u1[g][kk], wl, fmaf(u2[g][kk], wr, acc[g]));
        }
    }
    #pragma unroll
    for (int g = 0; g < G; ++g)
        atomicAdd(&emb_acc[g * OUT + j], acc[g]);
}

// pos -> graph index (or -1); robust to bool stored as bytes or int32
__global__ __launch_bounds__(256) void pos2graph_k(const unsigned char* __restrict__ is_node,
                                                   int* __restrict__ p2g) {
    int int_mode = (is_node[256] == 0);
    const int* in32 = (const int*)is_node;
    __shared__ int part[256];
    int t = threadIdx.x;
    unsigned char m[32];
    int c = 0;
    for (int i = 0; i < 32; ++i) {
        int idx = t * 32 + i;
        unsigned char v = int_mode ? (unsigned char)(in32[idx] != 0) : (unsigned char)(is_node[idx] != 0);
        m[i] = v;
        c += v ? 1 : 0;
    }
    part[t] = c;
    __syncthreads();
    for (int off = 1; off < 256; off <<= 1) {
        int v = (t >= off) ? part[t - off] : 0;
        __syncthreads();
        part[t] += v;
        __syncthreads();
    }
    int run = part[t] - c;
    for (int i = 0; i < 32; ++i) {
        int idx = t * 32 + i;
        p2g[idx] = m[i] ? (run < (G - 1) ? run : (G - 1)) : -1;
        if (m[i]) run++;
    }
}

// Final assembly, dtype-dual output
__global__ __launch_bounds__(256) void assemble_k(const int* __restrict__ p2g,
                                                  const int* __restrict__ input_ids,
                                                  const void* embedv,
                                                  const float* __restrict__ emb_acc,
                                                  const float* __restrict__ b2f,
                                                  const void* x,
                                                  void* outv) {
    int f32 = probe_f32(x);
    int row = blockIdx.x;
    int t = threadIdx.x;
    int gidx = p2g[row];
    if (f32) {
        float* orow = (float*)outv + (size_t)row * OUT;
        if (gidx >= 0) {
            const float* src = emb_acc + (size_t)gidx * OUT;
            #pragma unroll
            for (int i = 0; i < 4; ++i) {
                int base = (t + i * 256) * 4;
                f32x4 v;
                #pragma unroll
                for (int k = 0; k < 4; ++k) v[k] = src[base + k] + b2f[base + k];
                *(f32x4*)(orow + base) = v;
            }
        } else {
            const uint4* s4 = (const uint4*)((const float*)embedv + (size_t)input_ids[row] * OUT);
            uint4* d4 = (uint4*)orow;
            #pragma unroll
            for (int i = 0; i < 4; ++i) d4[t + i * 256] = s4[t + i * 256];
        }
    } else {
        bf16_t* orow = (bf16_t*)outv + (size_t)row * OUT;
        if (gidx >= 0) {
            const float* src = emb_acc + (size_t)gidx * OUT;
            #pragma unroll
            for (int i = 0; i < 2; ++i) {
                int base = (t + i * 256) * 8;
                bf16x8 v;
                #pragma unroll
                for (int jj = 0; jj < 8; ++jj)
                    v[jj] = (bf16_t)(src[base + jj] + b2f[base + jj]);
                *(bf16x8*)(orow + base) = v;
            }
        } else {
            const uint4* s4 = (const uint4*)((const bf16_t*)embedv + (size_t)input_ids[row] * OUT);
            uint4* d4 = (uint4*)orow;
            d4[t] = s4[t];
            d4[t + 256] = s4[t + 256];
        }
    }
}

// ---------------- launch ----------------
extern "C" void kernel_launch(void* const* d_in, const int* in_sizes, int n_in,
                              void* d_out, int out_size, void* d_ws, size_t ws_size,
                              hipStream_t stream) {
    const void* x     = d_in[0];
    const int*  ei    = (const int*)d_in[1];
    const int*  ids   = (const int*)d_in[2];
    const unsigned char* isn = (const unsigned char*)d_in[3];
    const void* Wl1   = d_in[4];
    const void* Wr1   = d_in[5];
    const void* b1    = d_in[6];
    const void* Wl2   = d_in[7];
    const void* Wr2   = d_in[8];
    const void* b2    = d_in[9];
    const void* embed = d_in[10];

    char* ws = (char*)d_ws;
    int*    cnt    = (int*)  (ws + WS_CNT);
    float*  wnode  = (float*)(ws + WS_WNODE);
    float*  hsum   = (float*)(ws + WS_HSUM);
    float*  wsum   = (float*)(ws + WS_WSUM);
    float*  emb    = (float*)(ws + WS_EMB);
    int*    rowptr = (int*)  (ws + WS_ROWPTR);
    int*    cursor = (int*)  (ws + WS_CURSOR);
    int*    p2g    = (int*)  (ws + WS_POS2G);
    float*  b1f    = (float*)(ws + WS_B1F);
    float*  b2f    = (float*)(ws + WS_B2F);
    int*    esrc   = (int*)  (ws + WS_ESRC);
    bf16_t* xbf    = (bf16_t*)(ws + WS_XBF);
    bf16_t* agg    = (bf16_t*)(ws + WS_AGG);
    bf16_t* wcatT  = (bf16_t*)(ws + WS_WCATT);

    hipMemsetAsync(ws + WS_CNT, 0, WS_ZERO_BYTES, stream);

    conv_x_k<<<4096 + 20, 256, 0, stream>>>(x, b1, b2, xbf, b1f, b2f);
    build_wcatT_k<<<HID, 256, 0, stream>>>(Wl1, Wr1, x, wcatT);

    count_edges_k<<<G * EE / 256, 256, 0, stream>>>(ei, cnt);
    scan_rowptr_k<<<G, 256, 0, stream>>>(cnt, rowptr, cursor);
    scatter_edges_k<<<G * EE / 256, 256, 0, stream>>>(ei, cnt, cursor, esrc, wnode);
    aggregate_k<<<G * 256, 256, 0, stream>>>(xbf, rowptr, cnt, esrc, agg);

    l1_gemm_k<<<dim3(8, 8, G), 256, 0, stream>>>(agg, xbf, wcatT, b1f, wnode, hsum, wsum);
    l2_gemv_k<<<dim3(16, 8), 256, 0, stream>>>(wsum, hsum, Wl2, Wr2, x, emb);

    pos2graph_k<<<1, 256, 0, stream>>>(isn, p2g);
    assemble_k<<<BB * SS, 256, 0, stream>>>(p2g, ids, embed, emb, b2f, x, d_out);
}

// Round 2
// 883.564 us; speedup vs baseline: 1.0591x; 1.0489x over previous
//
#include <hip/hip_runtime.h>
#include <hip/hip_bf16.h>
#include <stdint.h>

// Problem constants
#define G 32
#define NN 1024
#define EE 16384
#define FIN 128
#define HID 1024
#define OUT 4096
#define BB 32
#define SS 256

typedef __bf16 bf16_t;
typedef __attribute__((ext_vector_type(2))) __bf16 bf16x2;
typedef __attribute__((ext_vector_type(8))) __bf16 bf16x8;
typedef __attribute__((ext_vector_type(4))) float f32x4;

// ---------------- workspace layout (bytes) ----------------
// zeroed block (one memset of WS_ZERO_BYTES at WS_CNT):
#define WS_CNT      4096         // G*NN*4      = 131072
#define WS_WNODE    135168       // G*NN*4
#define WS_HSUM     266240       // G*NN*4
#define WS_WSUM     397312       // G*NN*4
#define WS_EMB      528384       // G*OUT*4     = 524288
#define WS_ZERO_BYTES 1048576    // covers cnt..emb exactly
#define WS_ROWPTR   1052672      // G*NN*4
#define WS_CURSOR   1183744      // G*NN*4
#define WS_POS2G    1314816      // BB*SS*4     = 32768
#define WS_B1F      1347584      // HID*4       = 4096
#define WS_B2F      1351680      // OUT*4       = 16384
#define WS_ESRC     1368064      // G*EE*4      = 2097152
#define WS_XBF      3465216      // G*NN*FIN*2  = 8388608
#define WS_AGG      11853824     // G*NN*FIN*2  = 8388608
#define WS_WCATT    20242432     // HID*256*2   = 524288

__device__ inline float ldf(const void* p, size_t i, int f32) {
    return f32 ? ((const float*)p)[i] : (float)((const bf16_t*)p)[i];
}

// ---------------- inline dtype probe ----------------
// Deterministic: every caller reads the SAME 1 KB window of node_features
// (L2-hot), so all blocks reach the same verdict with no flag round-trip.
// fp32 data: even bf16 slots are fp32 low-mantissa bits -> bits 13&14 both
// set w.p. 0.25/sample; 256 samples -> miss prob 0.75^256 ~ 2e-32.
// Genuine bf16 normals (|x| < 2^65) never have exp bits 7&6 both set.
__device__ inline int probe_f32(const void* xp) {
    const uint4* u = (const uint4*)xp;
    unsigned accm = 0;
    #pragma unroll 4
    for (int i = 0; i < 64; ++i) {
        uint4 v = u[i];
        accm |= (v.x & (v.x << 1));
        accm |= (v.y & (v.y << 1));
        accm |= (v.z & (v.z << 1));
        accm |= (v.w & (v.w << 1));
    }
    return (accm >> 14) & 1;  // bit14 = (low-short bit14 & bit13)
}

// async global->LDS, 16 B per lane
__device__ inline void gl_lds16(const bf16_t* g, bf16_t* l) {
    __builtin_amdgcn_global_load_lds(
        (const __attribute__((address_space(1))) void*)g,
        (__attribute__((address_space(3))) void*)l, 16, 0, 0);
}

// ---------------- merged front-end (all mutually independent work) ----------
// blocks [0,4096)        : canonicalize x -> bf16 xbf
// blocks [4096,4116)     : canonicalize b1,b2 -> fp32
// blocks [4116,5140)     : build WcatT [HID][256]
// blocks [5140,7188)     : count_edges (cnt must be pre-zeroed by memset)
// block  7188            : pos2graph
#define PREP_CONV_END   4096
#define PREP_BIAS_END   4116
#define PREP_WCAT_END   5140
#define PREP_CNT_END    7188
__global__ __launch_bounds__(256) void prep_k(const void* x, const void* b1,
                                              const void* b2, const void* Wl1,
                                              const void* Wr1,
                                              const int* __restrict__ ei,
                                              const unsigned char* __restrict__ is_node,
                                              bf16_t* __restrict__ xbf,
                                              float* __restrict__ b1f,
                                              float* __restrict__ b2f,
                                              bf16_t* __restrict__ wcatT,
                                              int* __restrict__ cnt,
                                              int* __restrict__ p2g) {
    int bx = blockIdx.x;
    if (bx < PREP_CONV_END) {
        int f32 = probe_f32(x);
        size_t i = ((size_t)bx * 256 + threadIdx.x) * 4;
        if (f32) {
            const float* xf = (const float*)x;
            bf16_t o0 = (bf16_t)xf[i], o1 = (bf16_t)xf[i + 1],
                   o2 = (bf16_t)xf[i + 2], o3 = (bf16_t)xf[i + 3];
            unsigned short p[4] = {*(unsigned short*)&o0, *(unsigned short*)&o1,
                                   *(unsigned short*)&o2, *(unsigned short*)&o3};
            *(uint2*)(xbf + i) = *(uint2*)p;
        } else {
            *(uint2*)(xbf + i) = *(const uint2*)((const bf16_t*)x + i);
        }
    } else if (bx < PREP_BIAS_END) {
        int f32 = probe_f32(x);
        int t = (bx - PREP_CONV_END) * 256 + threadIdx.x;
        if (t < HID) b1f[t] = ldf(b1, t, f32);
        else if (t < HID + OUT) b2f[t - HID] = ldf(b2, t - HID, f32);
    } else if (bx < PREP_WCAT_END) {
        int f32 = probe_f32(x);
        int n = bx - PREP_BIAS_END;
        int k = threadIdx.x;
        float v = (k < 128) ? ldf(Wl1, (size_t)k * HID + n, f32)
                            : ldf(Wr1, (size_t)(k - 128) * HID + n, f32);
        wcatT[n * 256 + k] = (bf16_t)v;
    } else if (bx < PREP_CNT_END) {
        int idx = (bx - PREP_WCAT_END) * 256 + threadIdx.x;
        int g = idx >> 14, e = idx & (EE - 1);
        int dst = ei[(g * 2 + 1) * EE + e];
        atomicAdd(&cnt[g * NN + dst], 1);
    } else {
        // pos -> graph index (or -1); robust to bool as bytes or int32
        int int_mode = (is_node[256] == 0);
        const int* in32 = (const int*)is_node;
        __shared__ int part[256];
        int t = threadIdx.x;
        unsigned char m[32];
        int c = 0;
        for (int i = 0; i < 32; ++i) {
            int idx = t * 32 + i;
            unsigned char v = int_mode ? (unsigned char)(in32[idx] != 0)
                                       : (unsigned char)(is_node[idx] != 0);
            m[i] = v;
            c += v ? 1 : 0;
        }
        part[t] = c;
        __syncthreads();
        for (int off = 1; off < 256; off <<= 1) {
            int v = (t >= off) ? part[t - off] : 0;
            __syncthreads();
            part[t] += v;
            __syncthreads();
        }
        int run = part[t] - c;
        for (int i = 0; i < 32; ++i) {
            int idx = t * 32 + i;
            p2g[idx] = m[i] ? (run < (G - 1) ? run : (G - 1)) : -1;
            if (m[i]) run++;
        }
    }
}

// ---------------- CSR build ----------------
__global__ __launch_bounds__(256) void scan_rowptr_k(const int* __restrict__ cnt,
                                                     int* __restrict__ rowptr,
                                                     int* __restrict__ cursor) {
    int g = blockIdx.x;
    const int* c = cnt + g * NN;
    __shared__ int part[256];
    int t = threadIdx.x;
    int c0 = c[t * 4], c1 = c[t * 4 + 1], c2 = c[t * 4 + 2], c3 = c[t * 4 + 3];
    int s = c0 + c1 + c2 + c3;
    part[t] = s;
    __syncthreads();
    for (int off = 1; off < 256; off <<= 1) {
        int v = (t >= off) ? part[t - off] : 0;
        __syncthreads();
        part[t] += v;
        __syncthreads();
    }
    int base = part[t] - s;
    int gi = g * NN + t * 4;
    int o0 = base, o1 = o0 + c0, o2 = o1 + c1, o3 = o2 + c2;
    rowptr[gi] = o0; rowptr[gi + 1] = o1; rowptr[gi + 2] = o2; rowptr[gi + 3] = o3;
    cursor[gi] = o0; cursor[gi + 1] = o1; cursor[gi + 2] = o2; cursor[gi + 3] = o3;
}

// fused: scatter edges into CSR + accumulate wnode[src] += 1/deg[dst]
__global__ __launch_bounds__(256) void scatter_edges_k(const int* __restrict__ ei,
                                                       const int* __restrict__ cnt,
                                                       int* __restrict__ cursor,
                                                       int* __restrict__ esrc,
                                                       float* __restrict__ wnode) {
    int idx = blockIdx.x * 256 + threadIdx.x;
    int g = idx >> 14, e = idx & (EE - 1);
    int src = ei[g * 2 * EE + e];
    int dst = ei[(g * 2 + 1) * EE + e];
    int c = cnt[g * NN + dst];
    atomicAdd(&wnode[g * NN + src], 1.0f / (float)(c > 1 ? c : 1));
    int p = atomicAdd(&cursor[g * NN + dst], 1);
    esrc[g * EE + p] = src;
}

// mean-aggregate xbf over incoming edges -> agg (bf16). One wave per node,
// bf16x2 per lane; start/deg wave-uniform -> scalar esrc walk.
__global__ __launch_bounds__(256) void aggregate_k(const bf16_t* __restrict__ x,
                                                   const int* __restrict__ rowptr,
                                                   const int* __restrict__ cnt,
                                                   const int* __restrict__ esrc,
                                                   bf16_t* __restrict__ agg) {
    int g = blockIdx.x >> 8;
    int nb = blockIdx.x & 255;
    int wave = threadIdx.x >> 6;
    int lane = threadIdx.x & 63;
    int n = nb * 4 + wave;
    int start = __builtin_amdgcn_readfirstlane(rowptr[g * NN + n]);
    int deg   = __builtin_amdgcn_readfirstlane(cnt[g * NN + n]);
    const bf16_t* xg = x + (size_t)g * NN * FIN;
    const int* es = esrc + g * EE;
    int f = lane * 2;
    float s0 = 0.f, s1 = 0.f;
    for (int i = 0; i < deg; ++i) {
        int s = es[start + i];
        bf16x2 v = *(const bf16x2*)(xg + s * FIN + f);
        s0 += (float)v[0];
        s1 += (float)v[1];
    }
    float inv = 1.0f / (float)(deg > 1 ? deg : 1);
    bf16x2 o;
    o[0] = (bf16_t)(s0 * inv);
    o[1] = (bf16_t)(s1 * inv);
    *(bf16x2*)(agg + ((size_t)g * NN + n) * FIN + f) = o;
}

// Layer-1 GEMM: relu([agg|x] @ [Wl1;Wr1] + b1) with fused plain/weighted
// row-sums. m97 structure: global_load_lds(16B) staging, linear [128][32] LDS.
__global__ __launch_bounds__(256) void l1_gemm_k(const bf16_t* __restrict__ agg,
                                                 const bf16_t* __restrict__ x,
                                                 const bf16_t* __restrict__ wcatT,
                                                 const float* __restrict__ b1f,
                                                 const float* __restrict__ wnode,
                                                 float* __restrict__ hsum,
                                                 float* __restrict__ wsum) {
    int nt = blockIdx.x, mt = blockIdx.y, g = blockIdx.z;
    __shared__ bf16_t As[128 * 32];
    __shared__ bf16_t Bs[128 * 32];
    int tid = threadIdx.x;
    int lane = tid & 63, wave = tid >> 6;
    int quad = lane >> 4, l16 = lane & 15;
    int m0 = (wave >> 1) * 64, n0 = (wave & 1) * 64;

    f32x4 acc[4][4] = {};
    const size_t arow = ((size_t)g * NN + (size_t)mt * 128) * FIN;
    const bf16_t* bslab = wcatT + (size_t)(nt * 128) * 256;

    int j0 = tid,        row0 = j0 >> 2, sl0 = (j0 & 3) * 8;
    int j1 = 256 + tid,  row1 = j1 >> 2, sl1 = (j1 & 3) * 8;

    for (int kc = 0; kc < 8; ++kc) {
        int k0 = kc * 32;
        const bf16_t* asrc = (k0 < 128) ? (agg + arow + k0) : (x + arow + (k0 - 128));
        const bf16_t* bsrc = bslab + k0;
        gl_lds16(asrc + (size_t)row0 * FIN + sl0, &As[j0 * 8]);
        gl_lds16(asrc + (size_t)row1 * FIN + sl1, &As[j1 * 8]);
        gl_lds16(bsrc + (size_t)row0 * 256 + sl0, &Bs[j0 * 8]);
        gl_lds16(bsrc + (size_t)row1 * 256 + sl1, &Bs[j1 * 8]);
        __syncthreads();  // drains vmcnt -> LDS tiles complete
        bf16x8 a[4], b[4];
        int kl = quad * 8;
        #pragma unroll
        for (int t4 = 0; t4 < 4; ++t4) {
            a[t4] = *(const bf16x8*)(&As[(m0 + t4 * 16 + l16) * 32 + kl]);
            b[t4] = *(const bf16x8*)(&Bs[(n0 + t4 * 16 + l16) * 32 + kl]);
        }
        #pragma unroll
        for (int ti = 0; ti < 4; ++ti)
            #pragma unroll
            for (int tj = 0; tj < 4; ++tj)
                acc[ti][tj] = __builtin_amdgcn_mfma_f32_16x16x32_bf16(a[ti], b[tj], acc[ti][tj], 0, 0, 0);
        __syncthreads();
    }

    const float* wn = wnode + (size_t)g * NN + mt * 128;
    #pragma unroll
    for (int tj = 0; tj < 4; ++tj) {
        int ng = nt * 128 + n0 + tj * 16 + l16;
        float bias = b1f[ng];
        float hs = 0.f, wsv = 0.f;
        #pragma unroll
        for (int ti = 0; ti < 4; ++ti) {
            int mb = m0 + ti * 16 + quad * 4;
            #pragma unroll
            for (int r = 0; r < 4; ++r) {
                float h = acc[ti][tj][r] + bias;
                h = h > 0.f ? h : 0.f;
                hs += h;
                wsv += wn[mb + r] * h;
            }
        }
        hs += __shfl_xor(hs, 16);  hs += __shfl_xor(hs, 32);
        wsv += __shfl_xor(wsv, 16); wsv += __shfl_xor(wsv, 32);
        if (quad == 0) {
            atomicAdd(&hsum[(size_t)g * HID + ng], hs);
            atomicAdd(&wsum[(size_t)g * HID + ng], wsv);
        }
    }
}

// Layer-2 collapsed GEMV (dtype-dual weight reads). Grid (16,16): 256 blocks
// so all CUs are busy; each block covers 64 k-rows x 256 j-cols.
__global__ __launch_bounds__(256) void l2_gemv_k(const float* __restrict__ wsum,
                                                 const float* __restrict__ hsum,
                                                 const void* Wl2v, const void* Wr2v,
                                                 const void* x,
                                                 float* __restrict__ emb_acc) {
    int f32 = probe_f32(x);
    int jc = blockIdx.x;   // 16
    int kc = blockIdx.y;   // 16 (64 rows each)
    int t = threadIdx.x;
    int j = jc * 256 + t;
    __shared__ float u1[G][64];
    __shared__ float u2[G][64];
    for (int i = 0; i < 8; ++i) {
        int idx = t + i * 256;
        int g = idx >> 6, kk = idx & 63;
        u1[g][kk] = wsum[g * HID + kc * 64 + kk] * (1.0f / 1024.0f);
        u2[g][kk] = hsum[g * HID + kc * 64 + kk] * (1.0f / 1024.0f);
    }
    __syncthreads();
    float acc[G] = {};
    if (f32) {
        const float* L = (const float*)Wl2v;
        const float* R = (const float*)Wr2v;
        for (int kk = 0; kk < 64; ++kk) {
            size_t krow = (size_t)(kc * 64 + kk);
            float wl = L[krow * OUT + j];
            float wr = R[krow * OUT + j];
            #pragma unroll
            for (int g = 0; g < G; ++g)
                acc[g] = fmaf(u1[g][kk], wl, fmaf(u2[g][kk], wr, acc[g]));
        }
    } else {
        const bf16_t* L = (const bf16_t*)Wl2v;
        const bf16_t* R = (const bf16_t*)Wr2v;
        for (int kk = 0; kk < 64; ++kk) {
            size_t krow = (size_t)(kc * 64 + kk);
            float wl = (float)L[krow * OUT + j];
            float wr = (float)R[krow * OUT + j];
            #pragma unroll
            for (int g = 0; g < G; ++g)
                acc[g] = fmaf(u1[g][kk], wl, fmaf(u2[g][kk], wr, acc[g]));
        }
    }
    #pragma unroll
    for (int g = 0; g < G; ++g)
        atomicAdd(&emb_acc[g * OUT + j], acc[g]);
}

// Final assembly, dtype-dual output
__global__ __launch_bounds__(256) void assemble_k(const int* __restrict__ p2g,
                                                  const int* __restrict__ input_ids,
                                                  const void* embedv,
                                                  const float* __restrict__ emb_acc,
                                                  const float* __restrict__ b2f,
                                                  const void* x,
                                                  void* outv) {
    int f32 = probe_f32(x);
    int row = blockIdx.x;
    int t = threadIdx.x;
    int gidx = p2g[row];
    if (f32) {
        float* orow = (float*)outv + (size_t)row * OUT;
        if (gidx >= 0) {
            const float* src = emb_acc + (size_t)gidx * OUT;
            #pragma unroll
            for (int i = 0; i < 4; ++i) {
                int base = (t + i * 256) * 4;
                f32x4 v;
                #pragma unroll
                for (int k = 0; k < 4; ++k) v[k] = src[base + k] + b2f[base + k];
                *(f32x4*)(orow + base) = v;
            }
        } else {
            const uint4* s4 = (const uint4*)((const float*)embedv + (size_t)input_ids[row] * OUT);
            uint4* d4 = (uint4*)orow;
            #pragma unroll
            for (int i = 0; i < 4; ++i) d4[t + i * 256] = s4[t + i * 256];
        }
    } else {
        bf16_t* orow = (bf16_t*)outv + (size_t)row * OUT;
        if (gidx >= 0) {
            const float* src = emb_acc + (size_t)gidx * OUT;
            #pragma unroll
            for (int i = 0; i < 2; ++i) {
                int base = (t + i * 256) * 8;
                bf16x8 v;
                #pragma unroll
                for (int jj = 0; jj < 8; ++jj)
                    v[jj] = (bf16_t)(src[base + jj] + b2f[base + jj]);
                *(bf16x8*)(orow + base) = v;
            }
        } else {
            const uint4* s4 = (const uint4*)((const bf16_t*)embedv + (size_t)input_ids[row] * OUT);
            uint4* d4 = (uint4*)orow;
            d4[t] = s4[t];
            d4[t + 256] = s4[t + 256];
        }
    }
}

// ---------------- launch ----------------
extern "C" void kernel_launch(void* const* d_in, const int* in_sizes, int n_in,
                              void* d_out, int out_size, void* d_ws, size_t ws_size,
                              hipStream_t stream) {
    const void* x     = d_in[0];
    const int*  ei    = (const int*)d_in[1];
    const int*  ids   = (const int*)d_in[2];
    const unsigned char* isn = (const unsigned char*)d_in[3];
    const void* Wl1   = d_in[4];
    const void* Wr1   = d_in[5];
    const void* b1    = d_in[6];
    const void* Wl2   = d_in[7];
    const void* Wr2   = d_in[8];
    const void* b2    = d_in[9];
    const void* embed = d_in[10];

    char* ws = (char*)d_ws;
    int*    cnt    = (int*)  (ws + WS_CNT);
    float*  wnode  = (float*)(ws + WS_WNODE);
    float*  hsum   = (float*)(ws + WS_HSUM);
    float*  wsum   = (float*)(ws + WS_WSUM);
    float*  emb    = (float*)(ws + WS_EMB);
    int*    rowptr = (int*)  (ws + WS_ROWPTR);
    int*    cursor = (int*)  (ws + WS_CURSOR);
    int*    p2g    = (int*)  (ws + WS_POS2G);
    float*  b1f    = (float*)(ws + WS_B1F);
    float*  b2f    = (float*)(ws + WS_B2F);
    int*    esrc   = (int*)  (ws + WS_ESRC);
    bf16_t* xbf    = (bf16_t*)(ws + WS_XBF);
    bf16_t* agg    = (bf16_t*)(ws + WS_AGG);
    bf16_t* wcatT  = (bf16_t*)(ws + WS_WCATT);

    hipMemsetAsync(ws + WS_CNT, 0, WS_ZERO_BYTES, stream);

    prep_k<<<PREP_CNT_END + 1, 256, 0, stream>>>(x, b1, b2, Wl1, Wr1, ei, isn,
                                                 xbf, b1f, b2f, wcatT, cnt, p2g);
    scan_rowptr_k<<<G, 256, 0, stream>>>(cnt, rowptr, cursor);
    scatter_edges_k<<<G * EE / 256, 256, 0, stream>>>(ei, cnt, cursor, esrc, wnode);
    aggregate_k<<<G * 256, 256, 0, stream>>>(xbf, rowptr, cnt, esrc, agg);

    l1_gemm_k<<<dim3(8, 8, G), 256, 0, stream>>>(agg, xbf, wcatT, b1f, wnode, hsum, wsum);
    l2_gemv_k<<<dim3(16, 16), 256, 0, stream>>>(wsum, hsum, Wl2, Wr2, x, emb);

    assemble_k<<<BB * SS, 256, 0, stream>>>(p2g, ids, embed, emb, b2f, x, d_out);
}

// Round 3
// 858.984 us; speedup vs baseline: 1.0894x; 1.0286x over previous
//
#include <hip/hip_runtime.h>
#include <hip/hip_bf16.h>
#include <stdint.h>

// Problem constants
#define G 32
#define NN 1024
#define EE 16384
#define FIN 128
#define HID 1024
#define OUT 4096
#define BB 32
#define SS 256
#define CAP 128   // fixed in-edge slot capacity; Poisson(16) => P(deg>=128) ~ e^-150

typedef __bf16 bf16_t;
typedef __attribute__((ext_vector_type(2))) __bf16 bf16x2;
typedef __attribute__((ext_vector_type(8))) __bf16 bf16x8;
typedef __attribute__((ext_vector_type(4))) float f32x4;

// ---------------- workspace layout (bytes) ----------------
// zeroed block (one memset of WS_ZERO_BYTES at WS_CNT):
#define WS_CNT      4096         // G*NN*4      = 131072
#define WS_WNODE    135168       // G*NN*4
#define WS_HSUM     266240       // G*NN*4
#define WS_WSUM     397312       // G*NN*4
#define WS_EMB      528384       // G*OUT*4     = 524288
#define WS_ZERO_BYTES 1048576    // covers cnt..emb exactly
#define WS_POS2G    1052672      // BB*SS*4     = 32768
#define WS_B1F      1085440      // HID*4       = 4096
#define WS_B2F      1089536      // OUT*4       = 16384
#define WS_XBF      1105920      // G*NN*FIN*2  = 8388608
#define WS_AGG      9494528      // G*NN*FIN*2  = 8388608
#define WS_WCATT    17883136     // HID*256*2   = 524288
#define WS_ESRC     18407424     // G*NN*CAP*4  = 16777216  (slot table)

__device__ inline float ldf(const void* p, size_t i, int f32) {
    return f32 ? ((const float*)p)[i] : (float)((const bf16_t*)p)[i];
}

// ---------------- inline dtype probe ----------------
// Deterministic: every caller reads the SAME 1 KB window of node_features
// (L2-hot), so all blocks reach the same verdict with no flag round-trip.
// fp32 data: even bf16 slots are fp32 low-mantissa bits -> bits 13&14 both
// set w.p. 0.25/sample; 256 samples -> miss prob 0.75^256 ~ 2e-32.
// Genuine bf16 normals (|x| < 2^65) never have exp bits 7&6 both set.
__device__ inline int probe_f32(const void* xp) {
    const uint4* u = (const uint4*)xp;
    unsigned accm = 0;
    #pragma unroll 4
    for (int i = 0; i < 64; ++i) {
        uint4 v = u[i];
        accm |= (v.x & (v.x << 1));
        accm |= (v.y & (v.y << 1));
        accm |= (v.z & (v.z << 1));
        accm |= (v.w & (v.w << 1));
    }
    return (accm >> 14) & 1;  // bit14 = (low-short bit14 & bit13)
}

// async global->LDS, 16 B per lane
__device__ inline void gl_lds16(const bf16_t* g, bf16_t* l) {
    __builtin_amdgcn_global_load_lds(
        (const __attribute__((address_space(1))) void*)g,
        (__attribute__((address_space(3))) void*)l, 16, 0, 0);
}

// ---------------- merged front-end (all mutually independent work) ----------
// block  0               : pos2graph
// blocks [1,2049)        : edge scatter into fixed-cap slots (cnt pre-zeroed)
// blocks [2049,6145)     : canonicalize x -> bf16 xbf
// blocks [6145,7169)     : build WcatT [HID][256]
// blocks [7169,7189)     : canonicalize b1,b2 -> fp32
#define PREP_SCAT_END 2049
#define PREP_CONV_END 6145
#define PREP_WCAT_END 7169
#define PREP_NBLK     7189
__global__ __launch_bounds__(256) void prep_k(const void* x, const void* b1,
                                              const void* b2, const void* Wl1,
                                              const void* Wr1,
                                              const int* __restrict__ ei,
                                              const unsigned char* __restrict__ is_node,
                                              bf16_t* __restrict__ xbf,
                                              float* __restrict__ b1f,
                                              float* __restrict__ b2f,
                                              bf16_t* __restrict__ wcatT,
                                              int* __restrict__ cnt,
                                              int* __restrict__ esrc,
                                              int* __restrict__ p2g) {
    int bx = blockIdx.x;
    if (bx == 0) {
        // pos -> graph index (or -1); robust to bool as bytes or int32
        int int_mode = (is_node[256] == 0);
        const int* in32 = (const int*)is_node;
        __shared__ int part[256];
        int t = threadIdx.x;
        unsigned char m[32];
        int c = 0;
        for (int i = 0; i < 32; ++i) {
            int idx = t * 32 + i;
            unsigned char v = int_mode ? (unsigned char)(in32[idx] != 0)
                                       : (unsigned char)(is_node[idx] != 0);
            m[i] = v;
            c += v ? 1 : 0;
        }
        part[t] = c;
        __syncthreads();
        for (int off = 1; off < 256; off <<= 1) {
            int v = (t >= off) ? part[t - off] : 0;
            __syncthreads();
            part[t] += v;
            __syncthreads();
        }
        int run = part[t] - c;
        for (int i = 0; i < 32; ++i) {
            int idx = t * 32 + i;
            p2g[idx] = m[i] ? (run < (G - 1) ? run : (G - 1)) : -1;
            if (m[i]) run++;
        }
    } else if (bx < PREP_SCAT_END) {
        int idx = (bx - 1) * 256 + threadIdx.x;
        int g = idx >> 14, e = idx & (EE - 1);
        int src = ei[g * 2 * EE + e];
        int dst = ei[(g * 2 + 1) * EE + e];
        int p = atomicAdd(&cnt[g * NN + dst], 1);
        if (p < CAP) esrc[((size_t)(g * NN + dst) << 7) + p] = src;
    } else if (bx < PREP_CONV_END) {
        int f32 = probe_f32(x);
        size_t i = ((size_t)(bx - PREP_SCAT_END) * 256 + threadIdx.x) * 4;
        if (f32) {
            const float* xf = (const float*)x;
            bf16_t o0 = (bf16_t)xf[i], o1 = (bf16_t)xf[i + 1],
                   o2 = (bf16_t)xf[i + 2], o3 = (bf16_t)xf[i + 3];
            unsigned short p[4] = {*(unsigned short*)&o0, *(unsigned short*)&o1,
                                   *(unsigned short*)&o2, *(unsigned short*)&o3};
            *(uint2*)(xbf + i) = *(uint2*)p;
        } else {
            *(uint2*)(xbf + i) = *(const uint2*)((const bf16_t*)x + i);
        }
    } else if (bx < PREP_WCAT_END) {
        int f32 = probe_f32(x);
        int n = bx - PREP_CONV_END;
        int k = threadIdx.x;
        float v = (k < 128) ? ldf(Wl1, (size_t)k * HID + n, f32)
                            : ldf(Wr1, (size_t)(k - 128) * HID + n, f32);
        wcatT[n * 256 + k] = (bf16_t)v;
    } else {
        int f32 = probe_f32(x);
        int t = (bx - PREP_WCAT_END) * 256 + threadIdx.x;
        if (t < HID) b1f[t] = ldf(b1, t, f32);
        else if (t < HID + OUT) b2f[t - HID] = ldf(b2, t - HID, f32);
    }
}

// mean-aggregate xbf over incoming edges -> agg (bf16), and accumulate
// wnode[src] += 1/deg(dst) (lane 0, fire-and-forget atomics). One wave per
// node, bf16x2 per lane; deg wave-uniform -> scalar slot walk.
__global__ __launch_bounds__(256) void aggregate_k(const bf16_t* __restrict__ x,
                                                   const int* __restrict__ cnt,
                                                   const int* __restrict__ esrc,
                                                   bf16_t* __restrict__ agg,
                                                   float* __restrict__ wnode) {
    int g = blockIdx.x >> 8;
    int nb = blockIdx.x & 255;
    int wave = threadIdx.x >> 6;
    int lane = threadIdx.x & 63;
    int n = nb * 4 + wave;
    int deg = __builtin_amdgcn_readfirstlane(cnt[g * NN + n]);
    int degw = deg < CAP ? deg : CAP;
    const bf16_t* xg = x + (size_t)g * NN * FIN;
    const int* es = esrc + ((size_t)(g * NN + n) << 7);
    float* wng = wnode + (size_t)g * NN;
    float inv = 1.0f / (float)(deg > 1 ? deg : 1);
    int f = lane * 2;
    float s0 = 0.f, s1 = 0.f;
    for (int i = 0; i < degw; ++i) {
        int s = es[i];
        bf16x2 v = *(const bf16x2*)(xg + s * FIN + f);
        s0 += (float)v[0];
        s1 += (float)v[1];
        if (lane == 0) atomicAdd(&wng[s], inv);
    }
    bf16x2 o;
    o[0] = (bf16_t)(s0 * inv);
    o[1] = (bf16_t)(s1 * inv);
    *(bf16x2*)(agg + ((size_t)g * NN + n) * FIN + f) = o;
}

// Layer-1 GEMM: relu([agg|x] @ [Wl1;Wr1] + b1) with fused plain/weighted
// row-sums. m97 structure: global_load_lds(16B) staging, linear [128][32] LDS.
__global__ __launch_bounds__(256) void l1_gemm_k(const bf16_t* __restrict__ agg,
                                                 const bf16_t* __restrict__ x,
                                                 const bf16_t* __restrict__ wcatT,
                                                 const float* __restrict__ b1f,
                                                 const float* __restrict__ wnode,
                                                 float* __restrict__ hsum,
                                                 float* __restrict__ wsum) {
    int nt = blockIdx.x, mt = blockIdx.y, g = blockIdx.z;
    __shared__ bf16_t As[128 * 32];
    __shared__ bf16_t Bs[128 * 32];
    int tid = threadIdx.x;
    int lane = tid & 63, wave = tid >> 6;
    int quad = lane >> 4, l16 = lane & 15;
    int m0 = (wave >> 1) * 64, n0 = (wave & 1) * 64;

    f32x4 acc[4][4] = {};
    const size_t arow = ((size_t)g * NN + (size_t)mt * 128) * FIN;
    const bf16_t* bslab = wcatT + (size_t)(nt * 128) * 256;

    int j0 = tid,        row0 = j0 >> 2, sl0 = (j0 & 3) * 8;
    int j1 = 256 + tid,  row1 = j1 >> 2, sl1 = (j1 & 3) * 8;

    for (int kc = 0; kc < 8; ++kc) {
        int k0 = kc * 32;
        const bf16_t* asrc = (k0 < 128) ? (agg + arow + k0) : (x + arow + (k0 - 128));
        const bf16_t* bsrc = bslab + k0;
        gl_lds16(asrc + (size_t)row0 * FIN + sl0, &As[j0 * 8]);
        gl_lds16(asrc + (size_t)row1 * FIN + sl1, &As[j1 * 8]);
        gl_lds16(bsrc + (size_t)row0 * 256 + sl0, &Bs[j0 * 8]);
        gl_lds16(bsrc + (size_t)row1 * 256 + sl1, &Bs[j1 * 8]);
        __syncthreads();  // drains vmcnt -> LDS tiles complete
        bf16x8 a[4], b[4];
        int kl = quad * 8;
        #pragma unroll
        for (int t4 = 0; t4 < 4; ++t4) {
            a[t4] = *(const bf16x8*)(&As[(m0 + t4 * 16 + l16) * 32 + kl]);
            b[t4] = *(const bf16x8*)(&Bs[(n0 + t4 * 16 + l16) * 32 + kl]);
        }
        #pragma unroll
        for (int ti = 0; ti < 4; ++ti)
            #pragma unroll
            for (int tj = 0; tj < 4; ++tj)
                acc[ti][tj] = __builtin_amdgcn_mfma_f32_16x16x32_bf16(a[ti], b[tj], acc[ti][tj], 0, 0, 0);
        __syncthreads();
    }

    const float* wn = wnode + (size_t)g * NN + mt * 128;
    #pragma unroll
    for (int tj = 0; tj < 4; ++tj) {
        int ng = nt * 128 + n0 + tj * 16 + l16;
        float bias = b1f[ng];
        float hs = 0.f, wsv = 0.f;
        #pragma unroll
        for (int ti = 0; ti < 4; ++ti) {
            int mb = m0 + ti * 16 + quad * 4;
            #pragma unroll
            for (int r = 0; r < 4; ++r) {
                float h = acc[ti][tj][r] + bias;
                h = h > 0.f ? h : 0.f;
                hs += h;
                wsv += wn[mb + r] * h;
            }
        }
        hs += __shfl_xor(hs, 16);  hs += __shfl_xor(hs, 32);
        wsv += __shfl_xor(wsv, 16); wsv += __shfl_xor(wsv, 32);
        if (quad == 0) {
            atomicAdd(&hsum[(size_t)g * HID + ng], hs);
            atomicAdd(&wsum[(size_t)g * HID + ng], wsv);
        }
    }
}

// Layer-2 collapsed GEMV (dtype-dual weight reads). Grid (16,16): 256 blocks
// so all CUs are busy; each block covers 64 k-rows x 256 j-cols.
__global__ __launch_bounds__(256) void l2_gemv_k(const float* __restrict__ wsum,
                                                 const float* __restrict__ hsum,
                                                 const void* Wl2v, const void* Wr2v,
                                                 const void* x,
                                                 float* __restrict__ emb_acc) {
    int f32 = probe_f32(x);
    int jc = blockIdx.x;   // 16
    int kc = blockIdx.y;   // 16 (64 rows each)
    int t = threadIdx.x;
    int j = jc * 256 + t;
    __shared__ float u1[G][64];
    __shared__ float u2[G][64];
    for (int i = 0; i < 8; ++i) {
        int idx = t + i * 256;
        int g = idx >> 6, kk = idx & 63;
        u1[g][kk] = wsum[g * HID + kc * 64 + kk] * (1.0f / 1024.0f);
        u2[g][kk] = hsum[g * HID + kc * 64 + kk] * (1.0f / 1024.0f);
    }
    __syncthreads();
    float acc[G] = {};
    if (f32) {
        const float* L = (const float*)Wl2v;
        const float* R = (const float*)Wr2v;
        for (int kk = 0; kk < 64; ++kk) {
            size_t krow = (size_t)(kc * 64 + kk);
            float wl = L[krow * OUT + j];
            float wr = R[krow * OUT + j];
            #pragma unroll
            for (int g = 0; g < G; ++g)
                acc[g] = fmaf(u1[g][kk], wl, fmaf(u2[g][kk], wr, acc[g]));
        }
    } else {
        const bf16_t* L = (const bf16_t*)Wl2v;
        const bf16_t* R = (const bf16_t*)Wr2v;
        for (int kk = 0; kk < 64; ++kk) {
            size_t krow = (size_t)(kc * 64 + kk);
            float wl = (float)L[krow * OUT + j];
            float wr = (float)R[krow * OUT + j];
            #pragma unroll
            for (int g = 0; g < G; ++g)
                acc[g] = fmaf(u1[g][kk], wl, fmaf(u2[g][kk], wr, acc[g]));
        }
    }
    #pragma unroll
    for (int g = 0; g < G; ++g)
        atomicAdd(&emb_acc[g * OUT + j], acc[g]);
}

// Final assembly, dtype-dual output
__global__ __launch_bounds__(256) void assemble_k(const int* __restrict__ p2g,
                                                  const int* __restrict__ input_ids,
                                                  const void* embedv,
                                                  const float* __restrict__ emb_acc,
                                                  const float* __restrict__ b2f,
                                                  const void* x,
                                                  void* outv) {
    int f32 = probe_f32(x);
    int row = blockIdx.x;
    int t = threadIdx.x;
    int gidx = p2g[row];
    if (f32) {
        float* orow = (float*)outv + (size_t)row * OUT;
        if (gidx >= 0) {
            const float* src = emb_acc + (size_t)gidx * OUT;
            #pragma unroll
            for (int i = 0; i < 4; ++i) {
                int base = (t + i * 256) * 4;
                f32x4 v;
                #pragma unroll
                for (int k = 0; k < 4; ++k) v[k] = src[base + k] + b2f[base + k];
                *(f32x4*)(orow + base) = v;
            }
        } else {
            const uint4* s4 = (const uint4*)((const float*)embedv + (size_t)input_ids[row] * OUT);
            uint4* d4 = (uint4*)orow;
            #pragma unroll
            for (int i = 0; i < 4; ++i) d4[t + i * 256] = s4[t + i * 256];
        }
    } else {
        bf16_t* orow = (bf16_t*)outv + (size_t)row * OUT;
        if (gidx >= 0) {
            const float* src = emb_acc + (size_t)gidx * OUT;
            #pragma unroll
            for (int i = 0; i < 2; ++i) {
                int base = (t + i * 256) * 8;
                bf16x8 v;
                #pragma unroll
                for (int jj = 0; jj < 8; ++jj)
                    v[jj] = (bf16_t)(src[base + jj] + b2f[base + jj]);
                *(bf16x8*)(orow + base) = v;
            }
        } else {
            const uint4* s4 = (const uint4*)((const bf16_t*)embedv + (size_t)input_ids[row] * OUT);
            uint4* d4 = (uint4*)orow;
            d4[t] = s4[t];
            d4[t + 256] = s4[t + 256];
        }
    }
}

// ---------------- launch ----------------
extern "C" void kernel_launch(void* const* d_in, const int* in_sizes, int n_in,
                              void* d_out, int out_size, void* d_ws, size_t ws_size,
                              hipStream_t stream) {
    const void* x     = d_in[0];
    const int*  ei    = (const int*)d_in[1];
    const int*  ids   = (const int*)d_in[2];
    const unsigned char* isn = (const unsigned char*)d_in[3];
    const void* Wl1   = d_in[4];
    const void* Wr1   = d_in[5];
    const void* b1    = d_in[6];
    const void* Wl2   = d_in[7];
    const void* Wr2   = d_in[8];
    const void* b2    = d_in[9];
    const void* embed = d_in[10];

    char* ws = (char*)d_ws;
    int*    cnt    = (int*)  (ws + WS_CNT);
    float*  wnode  = (float*)(ws + WS_WNODE);
    float*  hsum   = (float*)(ws + WS_HSUM);
    float*  wsum   = (float*)(ws + WS_WSUM);
    float*  emb    = (float*)(ws + WS_EMB);
    int*    p2g    = (int*)  (ws + WS_POS2G);
    float*  b1f    = (float*)(ws + WS_B1F);
    float*  b2f    = (float*)(ws + WS_B2F);
    bf16_t* xbf    = (bf16_t*)(ws + WS_XBF);
    bf16_t* agg    = (bf16_t*)(ws + WS_AGG);
    bf16_t* wcatT  = (bf16_t*)(ws + WS_WCATT);
    int*    esrc   = (int*)  (ws + WS_ESRC);

    hipMemsetAsync(ws + WS_CNT, 0, WS_ZERO_BYTES, stream);

    prep_k<<<PREP_NBLK, 256, 0, stream>>>(x, b1, b2, Wl1, Wr1, ei, isn,
                                          xbf, b1f, b2f, wcatT, cnt, esrc, p2g);
    aggregate_k<<<G * 256, 256, 0, stream>>>(xbf, cnt, esrc, agg, wnode);

    l1_gemm_k<<<dim3(8, 8, G), 256, 0, stream>>>(agg, xbf, wcatT, b1f, wnode, hsum, wsum);
    l2_gemv_k<<<dim3(16, 16), 256, 0, stream>>>(wsum, hsum, Wl2, Wr2, x, emb);

    assemble_k<<<BB * SS, 256, 0, stream>>>(p2g, ids, embed, emb, b2f, x, d_out);
}